// Round 8
// baseline (303.729 us; speedup 1.0000x reference)
//
#include <hip/hip_runtime.h>
#include <hip/hip_bf16.h>
#include <math.h>

#define N_NODES 100000
#define N_EDGES 1600000
#define HID 128
#define D_IN 6
#define NEG_SLOPE 0.2f

#define NB_BKT 128                       // nodes per bucket
#define NBKT 782                         // ceil(N_NODES / NB_BKT)
#define NBLK_P 200                       // partition blocks
#define EPB ((N_EDGES + NBLK_P - 1) / NBLK_P)   // 8000 edges per partition block
#define NHIST (NBKT * NBLK_P)            // 156400
#define S2_CAP 3072                      // max edges per bucket (mean 2048, +22 sigma)

// ---------------------------------------------------------------------------
// K_prep (1 block): w_as = w_gat@att_src (6), w_ad = w_gat@att_dst (6),
// dotwe = w_edge . att_edge
__global__ __launch_bounds__(128) void k_prep(
    const float* __restrict__ w_gat, const float* __restrict__ att_src,
    const float* __restrict__ att_dst, const float* __restrict__ w_edge,
    const float* __restrict__ att_edge, float* __restrict__ w_as,
    float* __restrict__ w_ad, float* __restrict__ dotwe)
{
    int tid = threadIdx.x;
    __shared__ float red[4];
    float as = att_src[tid], ad = att_dst[tid];

    float v = w_edge[tid] * att_edge[tid];
    for (int o = 32; o; o >>= 1) v += __shfl_down(v, o);
    if ((tid & 63) == 0) red[tid >> 6] = v;
    __syncthreads();
    if (tid == 0) dotwe[0] = red[0] + red[1];

#pragma unroll
    for (int i = 0; i < D_IN; ++i) {
        float wv = w_gat[i * HID + tid];
        float v1 = wv * as, v2 = wv * ad;
        for (int o = 32; o; o >>= 1) {
            v1 += __shfl_down(v1, o);
            v2 += __shfl_down(v2, o);
        }
        __syncthreads();
        if ((tid & 63) == 0) { red[(tid >> 6) * 2] = v1; red[(tid >> 6) * 2 + 1] = v2; }
        __syncthreads();
        if (tid == 0) { w_as[i] = red[0] + red[2]; w_ad[i] = red[1] + red[3]; }
    }
}

// ---------------------------------------------------------------------------
__global__ __launch_bounds__(256) void k_asrc(
    const float* __restrict__ x, const float* __restrict__ w_as,
    const float* __restrict__ w_ad, float* __restrict__ a_src,
    float* __restrict__ a_dst)
{
    int n = blockIdx.x * 256 + threadIdx.x;
    if (n >= N_NODES) return;
    float s0 = 0.f, s1 = 0.f;
#pragma unroll
    for (int i = 0; i < D_IN; ++i) {
        float xv = x[n * D_IN + i];
        s0 += xv * w_as[i];
        s1 += xv * w_ad[i];
    }
    a_src[n] = s0;
    a_dst[n] = s1;
}

// ---------------------------------------------------------------------------
// K_hist: per-block LDS histogram over dst-buckets (no device atomics)
__global__ __launch_bounds__(256) void k_hist(
    const int* __restrict__ dst, int* __restrict__ histG)
{
    __shared__ int h[NBKT];
    for (int b = threadIdx.x; b < NBKT; b += 256) h[b] = 0;
    __syncthreads();
    int e0 = blockIdx.x * EPB, e1 = min(e0 + EPB, N_EDGES);
    for (int e = e0 + threadIdx.x; e < e1; e += 256)
        atomicAdd(&h[dst[e] >> 7], 1);           // LDS atomic (CU-local)
    __syncthreads();
    for (int b = threadIdx.x; b < NBKT; b += 256)
        histG[b * NBLK_P + blockIdx.x] = h[b];   // bucket-major layout
}

// ---------------------------------------------------------------------------
// generic exclusive scan (3 kernels, 512-thread blocks), n arbitrary
__global__ __launch_bounds__(512) void k_scan1(
    const int* __restrict__ in, int* __restrict__ incl, int* __restrict__ bsums,
    int n)
{
    __shared__ int s[512];
    int tid = threadIdx.x;
    int i = blockIdx.x * 512 + tid;
    int v = (i < n) ? in[i] : 0;
    s[tid] = v;
    __syncthreads();
    for (int o = 1; o < 512; o <<= 1) {
        int t = (tid >= o) ? s[tid - o] : 0;
        __syncthreads();
        s[tid] += t;
        __syncthreads();
    }
    if (i < n) incl[i] = s[tid];
    if (tid == 511) bsums[blockIdx.x] = s[511];
}

__global__ __launch_bounds__(512) void k_scan2(
    const int* __restrict__ bsums, int* __restrict__ boffs, int nb)
{
    __shared__ int s[512];
    int tid = threadIdx.x;
    int v = (tid < nb) ? bsums[tid] : 0;
    s[tid] = v;
    __syncthreads();
    for (int o = 1; o < 512; o <<= 1) {
        int t = (tid >= o) ? s[tid - o] : 0;
        __syncthreads();
        s[tid] += t;
        __syncthreads();
    }
    if (tid < nb) boffs[tid] = s[tid] - v;  // exclusive
}

__global__ __launch_bounds__(512) void k_scan3(
    const int* __restrict__ in, const int* __restrict__ incl,
    const int* __restrict__ boffs, int* __restrict__ off, int n)
{
    int i = blockIdx.x * 512 + threadIdx.x;
    if (i < n) {
        int b = boffs[blockIdx.x];
        off[i] = b + incl[i] - in[i];
        if (i == n - 1) off[n] = b + incl[i];
    }
}

// ---------------------------------------------------------------------------
// K_part: stable partition into dst-buckets. Each (block,bucket) writes into
// its exclusive range [offP[b*200+blk], ...) via an LDS cursor -> no device
// atomics; block-private regions stay L2-resident (low write-amp).
// Also computes p = exp(leaky(logit)) and stores p_arr (original order).
__global__ __launch_bounds__(256) void k_part(
    const int* __restrict__ src, const int* __restrict__ dst,
    const float* __restrict__ ew, const float* __restrict__ a_src,
    const float* __restrict__ a_dst, const float* __restrict__ dotwe,
    const int* __restrict__ offP, float* __restrict__ p_arr,
    uint2* __restrict__ rec)
{
    __shared__ int curs[NBKT];
    for (int b = threadIdx.x; b < NBKT; b += 256)
        curs[b] = offP[b * NBLK_P + blockIdx.x];
    __syncthreads();
    float dw = dotwe[0];
    int e0 = blockIdx.x * EPB, e1 = min(e0 + EPB, N_EDGES);
    for (int e = e0 + threadIdx.x; e < e1; e += 256) {
        int d = dst[e], s = src[e];
        float lg = a_src[s] + a_dst[d] + dw * ew[e];
        lg = (lg >= 0.f) ? lg : NEG_SLOPE * lg;
        float p = __expf(lg);
        p_arr[e] = p;
        int pos = atomicAdd(&curs[d >> 7], 1);   // LDS atomic
        rec[pos] = make_uint2(((unsigned)(d & 127) << 17) | (unsigned)s,
                              __float_as_uint(p));
    }
}

// ---------------------------------------------------------------------------
// K_s2: one block per bucket. LDS counting-sort (local bases via LDS scan),
// per-node denom, alpha normalize, coalesced CSR writeout, xagg, off, denomG.
__global__ __launch_bounds__(256) void k_s2(
    const int* __restrict__ offP, const uint2* __restrict__ rec,
    const float* __restrict__ x, uint2* __restrict__ sa_srt,
    float* __restrict__ xagg8, float* __restrict__ denomG,
    int* __restrict__ off)
{
    __shared__ uint2 srt[S2_CAP];
    __shared__ int cntL[NB_BKT], fillL[NB_BKT], baseL[NB_BKT + 1];
    __shared__ int sc[NB_BKT];
    __shared__ float rden[NB_BKT];
    int b = blockIdx.x, tid = threadIdx.x;
    int g0 = offP[b * NBLK_P];
    int g1 = offP[(b + 1) * NBLK_P];     // b==NBKT-1 -> offP[NHIST] == N_EDGES
    int len = min(g1 - g0, S2_CAP);

    if (tid < NB_BKT) { cntL[tid] = 0; fillL[tid] = 0; }
    __syncthreads();

    // pass 1: count (records re-read from L2)
    for (int i = tid; i < len; i += 256)
        atomicAdd(&cntL[rec[g0 + i].x >> 17], 1);
    __syncthreads();

    // LDS scan over 128 counts -> baseL (exclusive)
    {
        int v = (tid < NB_BKT) ? cntL[tid] : 0;
        if (tid < NB_BKT) sc[tid] = v;
        __syncthreads();
        for (int o = 1; o < NB_BKT; o <<= 1) {
            int t = (tid >= o && tid < NB_BKT) ? sc[tid - o] : 0;
            __syncthreads();
            if (tid < NB_BKT) sc[tid] += t;
            __syncthreads();
        }
        if (tid < NB_BKT) baseL[tid + 1] = sc[tid];
        if (tid == 0) baseL[0] = 0;
    }
    __syncthreads();

    // pass 2: place into sorted LDS order
    for (int i = tid; i < len; i += 256) {
        uint2 r = rec[g0 + i];
        int dl = r.x >> 17;
        int p = baseL[dl] + atomicAdd(&fillL[dl], 1);
        if (p < S2_CAP) srt[p] = r;
    }
    __syncthreads();

    // per-node denom
    if (tid < NB_BKT) {
        int s0 = baseL[tid], s1 = baseL[tid + 1];
        float dsum = 0.f;
        for (int j = s0; j < s1; ++j) dsum += __uint_as_float(srt[j].y);
        int n = b * NB_BKT + tid;
        if (n < N_NODES) denomG[n] = dsum;
        rden[tid] = 1.0f / fmaxf(dsum, 1e-16f);
    }
    __syncthreads();

    // normalize alpha in LDS + coalesced CSR writeout {src, alpha}
    for (int i = tid; i < len; i += 256) {
        uint2 r = srt[i];
        int dl = r.x >> 17;
        float a = __uint_as_float(r.y) * rden[dl];
        srt[i].y = __float_as_uint(a);
        sa_srt[g0 + i] = make_uint2(r.x & 0x1FFFFu, __float_as_uint(a));
    }
    __syncthreads();

    // xagg (6-dim weighted x sum) + off
    if (tid < NB_BKT) {
        int n = b * NB_BKT + tid;
        if (n < N_NODES) {
            int s0 = baseL[tid], s1 = baseL[tid + 1];
            float ax0 = 0, ax1 = 0, ax2 = 0, ax3 = 0, ax4 = 0, ax5 = 0;
            for (int j = s0; j < s1; ++j) {
                uint2 r = srt[j];
                float a = __uint_as_float(r.y);
                const float2* xp = (const float2*)(x + (size_t)(r.x & 0x1FFFFu) * D_IN);
                float2 q0 = xp[0], q1 = xp[1], q2 = xp[2];
                ax0 += a * q0.x; ax1 += a * q0.y; ax2 += a * q1.x;
                ax3 += a * q1.y; ax4 += a * q2.x; ax5 += a * q2.y;
            }
            float dv = (s1 > s0) ? 1.0f : 0.0f;   // sum(alpha)=1 -> dinv=1
            float* xo = xagg8 + (size_t)n * 8;
            float4 lo = {dv, ax0, ax1, ax2};
            float4 hi = {ax3, ax4, ax5, 0.f};
            *(float4*)xo = lo;
            *(float4*)(xo + 4) = hi;
            off[n] = g0 + s0;
        }
    }
    if (b == NBKT - 1 && tid == 0) off[N_NODES] = g1;
}

// ---------------------------------------------------------------------------
// K_alpha: original-order alpha output (coalesced; denom gathered, L3-resident)
__global__ __launch_bounds__(256) void k_alpha(
    const float* __restrict__ p_arr, const int* __restrict__ dst,
    const float* __restrict__ denomG, float* __restrict__ alpha_out)
{
    int e = blockIdx.x * 256 + threadIdx.x;
    if (e >= N_EDGES) return;
    alpha_out[e] = p_arr[e] / fmaxf(denomG[dst[e]], 1e-16f);
}

// ---------------------------------------------------------------------------
// K_gcn_gather (2-phase): 4 nodes/block.
// P1: lane-per-edge parallel gather of {dinv_s*alpha, xagg[0..5]} -> LDS
//     (all 256 threads stage).
// P2: wave-per-node, 2 features/lane, broadcast ds_read_b128, per-feature acc.
#define GCAP 256
__global__ __launch_bounds__(256) void k_gcn_gather(
    const uint2* __restrict__ sa_srt, const int* __restrict__ off,
    const float* __restrict__ xagg8, const float* __restrict__ w_gat,
    const float* __restrict__ b_gat, float* __restrict__ agg)
{
    __shared__ float lds[GCAP * 12];
    int tid = threadIdx.x;
    int n0 = blockIdx.x * 4;
    int wid = tid >> 6, l = tid & 63;
    int n = n0 + wid;
    int beg0 = off[n0];
    int total = off[n0 + 4] - beg0;
    int nb = off[n] - beg0, ne = off[n + 1] - beg0;

    int kA = l, kB = l + 64;
    float wA0 = w_gat[0 * HID + kA], wA1 = w_gat[1 * HID + kA], wA2 = w_gat[2 * HID + kA];
    float wA3 = w_gat[3 * HID + kA], wA4 = w_gat[4 * HID + kA], wA5 = w_gat[5 * HID + kA];
    float wB0 = w_gat[0 * HID + kB], wB1 = w_gat[1 * HID + kB], wB2 = w_gat[2 * HID + kB];
    float wB3 = w_gat[3 * HID + kB], wB4 = w_gat[4 * HID + kB], wB5 = w_gat[5 * HID + kB];
    float bA = b_gat[kA], bB = b_gat[kB];
    float accA = 0.f, accB = 0.f;

    for (int base = 0; base < total; base += GCAP) {
        int cnt = min(GCAP, total - base);
        __syncthreads();
        if (tid < cnt) {
            int j = beg0 + base + tid;
            uint2 sa = sa_srt[j];                  // coalesced 8B
            float a = __uint_as_float(sa.y);
            const float4* xp = (const float4*)(xagg8 + (size_t)sa.x * 8);
            float4 lo = xp[0], hi = xp[1];         // {dinv_s,x0,x1,x2},{x3,x4,x5,-}
            float4 w0 = {lo.x * a, lo.y, lo.z, lo.w};
            float4 w1 = {hi.x, hi.y, hi.z, 0.f};
            *(float4*)(lds + tid * 12) = w0;
            *(float4*)(lds + tid * 12 + 4) = w1;
        }
        __syncthreads();
        int lo_t = nb - base; if (lo_t < 0) lo_t = 0;
        int hi_t = ne - base; if (hi_t > cnt) hi_t = cnt;
        for (int t = lo_t; t < hi_t; ++t) {
            float4 e0 = *(const float4*)(lds + t * 12);
            float4 e1 = *(const float4*)(lds + t * 12 + 4);
            float hA = bA, hB = bB;
            hA = fmaf(e0.y, wA0, hA); hB = fmaf(e0.y, wB0, hB);
            hA = fmaf(e0.z, wA1, hA); hB = fmaf(e0.z, wB1, hB);
            hA = fmaf(e0.w, wA2, hA); hB = fmaf(e0.w, wB2, hB);
            hA = fmaf(e1.x, wA3, hA); hB = fmaf(e1.x, wB3, hB);
            hA = fmaf(e1.y, wA4, hA); hB = fmaf(e1.y, wB4, hB);
            hA = fmaf(e1.z, wA5, hA); hB = fmaf(e1.z, wB5, hB);
            hA = fmaxf(hA, 0.f); hB = fmaxf(hB, 0.f);
            accA = fmaf(e0.x, hA, accA); accB = fmaf(e0.x, hB, accB);
        }
    }
    float dn = xagg8[(size_t)n * 8];
    agg[(size_t)n * HID + kA] = dn * accA;
    agg[(size_t)n * HID + kB] = dn * accB;
}

// ---------------------------------------------------------------------------
// K_dense2 (LDS-tiled GEMM): h2 = relu(agg @ w_gcn + b_gcn); out = h2 @ w_out
// + b_out. M=128 nodes x N=128 x K-chunks of 32, 256 threads, 8x8 register
// tile per thread. Per k-step: 4 ds_read_b128 per 64 FMA -> VALU-bound; both
// operand streams come from LDS (no exposed L2 latency in the inner loop).
// LDS 33 KB -> 4 blocks/CU.
#define DM 128
#define DK 32
__global__ __launch_bounds__(256, 4) void k_dense2(
    const float* __restrict__ agg, const float* __restrict__ w_gcn,
    const float* __restrict__ b_gcn, const float* __restrict__ w_out,
    const float* __restrict__ b_out, float* __restrict__ out)
{
    __shared__ float As[DK][DM + 4];   // [k][m]
    __shared__ float Bs[DK][HID];      // [k][n]
    int tid = threadIdx.x;
    int m0 = blockIdx.x * DM;
    int tx = tid & 15;            // col group: cols tx*8 .. tx*8+7
    int ty = tid >> 4;            // row group: rows ty*8 .. ty*8+7

    float acc[8][8];
#pragma unroll
    for (int r = 0; r < 8; ++r)
#pragma unroll
        for (int j = 0; j < 8; ++j) acc[r][j] = 0.f;

    for (int k0 = 0; k0 < HID; k0 += DK) {
        // stage A: agg[m0+m][k0+k] -> As[k][m]  (128m x 32k, coalesced f4)
#pragma unroll
        for (int q = 0; q < 4; ++q) {
            int idx4 = tid + q * 256;
            int m = idx4 >> 3;             // 8 float4 per row
            int k4 = (idx4 & 7) * 4;
            int gm = m0 + m;
            float4 v = (gm < N_NODES)
                ? *(const float4*)(agg + (size_t)gm * HID + k0 + k4)
                : make_float4(0.f, 0.f, 0.f, 0.f);
            As[k4 + 0][m] = v.x;
            As[k4 + 1][m] = v.y;
            As[k4 + 2][m] = v.z;
            As[k4 + 3][m] = v.w;
        }
        // stage B: w_gcn[k0+k][n] -> Bs[k][n]  (32k x 128n, coalesced f4)
#pragma unroll
        for (int q = 0; q < 4; ++q) {
            int idx4 = tid + q * 256;
            int k = idx4 >> 5;             // 32 float4 per row
            int n4 = (idx4 & 31) * 4;
            *(float4*)&Bs[k][n4] = *(const float4*)(w_gcn + (size_t)(k0 + k) * HID + n4);
        }
        __syncthreads();
#pragma unroll 4
        for (int k = 0; k < DK; ++k) {
            float4 w0 = *(const float4*)&Bs[k][tx * 8];
            float4 w1 = *(const float4*)&Bs[k][tx * 8 + 4];
            float4 h0 = *(const float4*)&As[k][ty * 8];
            float4 h1 = *(const float4*)&As[k][ty * 8 + 4];
            float hv[8] = {h0.x, h0.y, h0.z, h0.w, h1.x, h1.y, h1.z, h1.w};
            float wv[8] = {w0.x, w0.y, w0.z, w0.w, w1.x, w1.y, w1.z, w1.w};
#pragma unroll
            for (int r = 0; r < 8; ++r)
#pragma unroll
                for (int j = 0; j < 8; ++j)
                    acc[r][j] = fmaf(hv[r], wv[j], acc[r][j]);
        }
        __syncthreads();
    }

    // epilogue: bias + relu + 2-col head, reduce over the 16 col-groups
    float bb[8], wo0[8], wo1[8];
#pragma unroll
    for (int j = 0; j < 8; ++j) {
        int c = tx * 8 + j;
        bb[j] = b_gcn[c];
        wo0[j] = w_out[c * 2 + 0];
        wo1[j] = w_out[c * 2 + 1];
    }
#pragma unroll
    for (int r = 0; r < 8; ++r) {
        float p0 = 0.f, p1 = 0.f;
#pragma unroll
        for (int j = 0; j < 8; ++j) {
            float h2 = fmaxf(acc[r][j] + bb[j], 0.f);
            p0 = fmaf(h2, wo0[j], p0);
            p1 = fmaf(h2, wo1[j], p1);
        }
        // butterfly over tx (16 lanes within the wave's 64; masks stay <16)
        p0 += __shfl_xor(p0, 1);  p1 += __shfl_xor(p1, 1);
        p0 += __shfl_xor(p0, 2);  p1 += __shfl_xor(p1, 2);
        p0 += __shfl_xor(p0, 4);  p1 += __shfl_xor(p1, 4);
        p0 += __shfl_xor(p0, 8);  p1 += __shfl_xor(p1, 8);
        if (tx == 0) {
            int gm = m0 + ty * 8 + r;
            if (gm < N_NODES) {
                out[(size_t)gm * 2 + 0] = p0 + b_out[0];
                out[(size_t)gm * 2 + 1] = p1 + b_out[1];
            }
        }
    }
}

// ---------------------------------------------------------------------------
// K_copy_ei: edge_index (int) -> float output, vectorized int4 -> float4
__global__ __launch_bounds__(256) void k_copy_ei(
    const int* __restrict__ ei, float* __restrict__ out_ei)
{
    int i = blockIdx.x * 256 + threadIdx.x;   // quad index
    if (i < (2 * N_EDGES) / 4) {
        int4 v = ((const int4*)ei)[i];
        float4 f = {(float)v.x, (float)v.y, (float)v.z, (float)v.w};
        ((float4*)out_ei)[i] = f;
    }
}

// ---------------------------------------------------------------------------
extern "C" void kernel_launch(void* const* d_in, const int* in_sizes, int n_in,
                              void* d_out, int out_size, void* d_ws, size_t ws_size,
                              hipStream_t stream)
{
    const float* x        = (const float*)d_in[0];
    const int*   ei       = (const int*)d_in[1];
    const float* ew       = (const float*)d_in[2];
    const float* w_gat    = (const float*)d_in[3];
    const float* att_src  = (const float*)d_in[4];
    const float* att_dst  = (const float*)d_in[5];
    const float* w_edge   = (const float*)d_in[6];
    const float* att_edge = (const float*)d_in[7];
    const float* b_gat    = (const float*)d_in[8];
    const float* w_gcn    = (const float*)d_in[9];
    const float* b_gcn    = (const float*)d_in[10];
    const float* w_out    = (const float*)d_in[11];
    const float* b_out    = (const float*)d_in[12];

    const int* src = ei;
    const int* dst = ei + N_EDGES;

    float* out_head  = (float*)d_out;
    float* out_ei    = out_head + 2 * N_NODES;
    float* out_alpha = out_ei + 2 * N_EDGES;

    char* ws = (char*)d_ws;
    size_t o = 0;
    auto alloc = [&](size_t bytes) -> char* {
        char* p = ws + o;
        o = (o + bytes + 255) & ~(size_t)255;
        return p;
    };
    float* agg    = (float*)alloc((size_t)N_NODES * HID * 4);   // 51.2 MB
    uint2* rec    = (uint2*)alloc((size_t)N_EDGES * 8);         // 12.8 MB
    uint2* sa_srt = (uint2*)alloc((size_t)N_EDGES * 8);         // 12.8 MB
    float* p_arr  = (float*)alloc((size_t)N_EDGES * 4);         // 6.4 MB
    float* xagg8  = (float*)alloc((size_t)N_NODES * 8 * 4);     // 3.2 MB
    int*   histG  = (int*)alloc((size_t)NHIST * 4);             // 0.63 MB
    int*   incl   = (int*)alloc((size_t)NHIST * 4);
    int*   offP   = (int*)alloc((size_t)(NHIST + 1) * 4);
    float* a_src  = (float*)alloc(N_NODES * 4);
    float* a_dst  = (float*)alloc(N_NODES * 4);
    float* denomG = (float*)alloc(N_NODES * 4);
    int*   off    = (int*)alloc((N_NODES + 1) * 4);
    int*   bsums  = (int*)alloc(512 * 4);
    int*   boffs  = (int*)alloc(512 * 4);
    float* w_as   = (float*)alloc(D_IN * 4);
    float* w_ad   = (float*)alloc(D_IN * 4);
    float* dotwe  = (float*)alloc(4);
    (void)ws_size; (void)out_size; (void)n_in; (void)in_sizes;

    const int NB_NODE = (N_NODES + 255) / 256;          // 391
    const int NB_EDGE = (N_EDGES + 255) / 256;          // 6250
    const int NB_SCANP = (NHIST + 511) / 512;           // 306

    k_prep<<<1, 128, 0, stream>>>(w_gat, att_src, att_dst, w_edge, att_edge,
                                  w_as, w_ad, dotwe);
    k_asrc<<<NB_NODE, 256, 0, stream>>>(x, w_as, w_ad, a_src, a_dst);
    k_hist<<<NBLK_P, 256, 0, stream>>>(dst, histG);
    k_scan1<<<NB_SCANP, 512, 0, stream>>>(histG, incl, bsums, NHIST);
    k_scan2<<<1, 512, 0, stream>>>(bsums, boffs, NB_SCANP);
    k_scan3<<<NB_SCANP, 512, 0, stream>>>(histG, incl, boffs, offP, NHIST);
    k_part<<<NBLK_P, 256, 0, stream>>>(src, dst, ew, a_src, a_dst, dotwe,
                                       offP, p_arr, rec);
    k_s2<<<NBKT, 256, 0, stream>>>(offP, rec, x, sa_srt, xagg8, denomG, off);
    k_alpha<<<NB_EDGE, 256, 0, stream>>>(p_arr, dst, denomG, out_alpha);
    k_gcn_gather<<<N_NODES / 4, 256, 0, stream>>>(
        sa_srt, off, xagg8, w_gat, b_gat, agg);
    k_dense2<<<(N_NODES + DM - 1) / DM, 256, 0, stream>>>(
        agg, w_gcn, b_gcn, w_out, b_out, out_head);
    k_copy_ei<<<(2 * N_EDGES) / 4 / 256 + 1, 256, 0, stream>>>(ei, out_ei);
}

// Round 9
// 297.513 us; speedup vs baseline: 1.0209x; 1.0209x over previous
//
#include <hip/hip_runtime.h>
#include <hip/hip_bf16.h>
#include <math.h>

#define N_NODES 100000
#define N_EDGES 1600000
#define HID 128
#define D_IN 6
#define NEG_SLOPE 0.2f

#define NB_BKT 128                       // nodes per bucket
#define NBKT 782                         // ceil(N_NODES / NB_BKT)
#define NBLK_P 256                       // partition blocks (1024 thr each)
#define EPB ((N_EDGES + NBLK_P - 1) / NBLK_P)   // 6250 edges per partition block
#define NHIST (NBKT * NBLK_P)            // 200192
#define S2_CAP 3072                      // max edges per bucket (mean 2048, +22 sigma)

// ---------------------------------------------------------------------------
// K_prep (1 block): w_as = w_gat@att_src (6), w_ad = w_gat@att_dst (6),
// dotwe = w_edge . att_edge
__global__ __launch_bounds__(128) void k_prep(
    const float* __restrict__ w_gat, const float* __restrict__ att_src,
    const float* __restrict__ att_dst, const float* __restrict__ w_edge,
    const float* __restrict__ att_edge, float* __restrict__ w_as,
    float* __restrict__ w_ad, float* __restrict__ dotwe)
{
    int tid = threadIdx.x;
    __shared__ float red[4];
    float as = att_src[tid], ad = att_dst[tid];

    float v = w_edge[tid] * att_edge[tid];
    for (int o = 32; o; o >>= 1) v += __shfl_down(v, o);
    if ((tid & 63) == 0) red[tid >> 6] = v;
    __syncthreads();
    if (tid == 0) dotwe[0] = red[0] + red[1];

#pragma unroll
    for (int i = 0; i < D_IN; ++i) {
        float wv = w_gat[i * HID + tid];
        float v1 = wv * as, v2 = wv * ad;
        for (int o = 32; o; o >>= 1) {
            v1 += __shfl_down(v1, o);
            v2 += __shfl_down(v2, o);
        }
        __syncthreads();
        if ((tid & 63) == 0) { red[(tid >> 6) * 2] = v1; red[(tid >> 6) * 2 + 1] = v2; }
        __syncthreads();
        if (tid == 0) { w_as[i] = red[0] + red[2]; w_ad[i] = red[1] + red[3]; }
    }
}

// ---------------------------------------------------------------------------
__global__ __launch_bounds__(256) void k_asrc(
    const float* __restrict__ x, const float* __restrict__ w_as,
    const float* __restrict__ w_ad, float* __restrict__ a_src,
    float* __restrict__ a_dst)
{
    int n = blockIdx.x * 256 + threadIdx.x;
    if (n >= N_NODES) return;
    float s0 = 0.f, s1 = 0.f;
#pragma unroll
    for (int i = 0; i < D_IN; ++i) {
        float xv = x[n * D_IN + i];
        s0 += xv * w_as[i];
        s1 += xv * w_ad[i];
    }
    a_src[n] = s0;
    a_dst[n] = s1;
}

// ---------------------------------------------------------------------------
// K_hist: per-block LDS histogram over dst-buckets (no device atomics)
__global__ __launch_bounds__(1024) void k_hist(
    const int* __restrict__ dst, int* __restrict__ histG)
{
    __shared__ int h[NBKT];
    for (int b = threadIdx.x; b < NBKT; b += 1024) h[b] = 0;
    __syncthreads();
    int e0 = blockIdx.x * EPB, e1 = min(e0 + EPB, N_EDGES);
    for (int e = e0 + threadIdx.x; e < e1; e += 1024)
        atomicAdd(&h[dst[e] >> 7], 1);           // LDS atomic (CU-local)
    __syncthreads();
    for (int b = threadIdx.x; b < NBKT; b += 1024)
        histG[b * NBLK_P + blockIdx.x] = h[b];   // bucket-major layout
}

// ---------------------------------------------------------------------------
// generic exclusive scan (3 kernels, 512-thread blocks), n arbitrary
__global__ __launch_bounds__(512) void k_scan1(
    const int* __restrict__ in, int* __restrict__ incl, int* __restrict__ bsums,
    int n)
{
    __shared__ int s[512];
    int tid = threadIdx.x;
    int i = blockIdx.x * 512 + tid;
    int v = (i < n) ? in[i] : 0;
    s[tid] = v;
    __syncthreads();
    for (int o = 1; o < 512; o <<= 1) {
        int t = (tid >= o) ? s[tid - o] : 0;
        __syncthreads();
        s[tid] += t;
        __syncthreads();
    }
    if (i < n) incl[i] = s[tid];
    if (tid == 511) bsums[blockIdx.x] = s[511];
}

__global__ __launch_bounds__(512) void k_scan2(
    const int* __restrict__ bsums, int* __restrict__ boffs, int nb)
{
    __shared__ int s[512];
    int tid = threadIdx.x;
    int v = (tid < nb) ? bsums[tid] : 0;
    s[tid] = v;
    __syncthreads();
    for (int o = 1; o < 512; o <<= 1) {
        int t = (tid >= o) ? s[tid - o] : 0;
        __syncthreads();
        s[tid] += t;
        __syncthreads();
    }
    if (tid < nb) boffs[tid] = s[tid] - v;  // exclusive
}

__global__ __launch_bounds__(512) void k_scan3(
    const int* __restrict__ in, const int* __restrict__ incl,
    const int* __restrict__ boffs, int* __restrict__ off, int n)
{
    int i = blockIdx.x * 512 + threadIdx.x;
    if (i < n) {
        int b = boffs[blockIdx.x];
        off[i] = b + incl[i] - in[i];
        if (i == n - 1) off[n] = b + incl[i];
    }
}

// ---------------------------------------------------------------------------
// K_part: stable partition into dst-buckets. Each (block,bucket) writes into
// its exclusive range (~8 records = 1 cache line) via an LDS cursor -> no
// device atomics, line-local writes. 1024 thr/block x 256 blocks = 4096 waves
// resident for latency hiding of the random a_src/a_dst gathers.
// Also computes p = exp(leaky(logit)) and stores p_arr (original order).
__global__ __launch_bounds__(1024) void k_part(
    const int* __restrict__ src, const int* __restrict__ dst,
    const float* __restrict__ ew, const float* __restrict__ a_src,
    const float* __restrict__ a_dst, const float* __restrict__ dotwe,
    const int* __restrict__ offP, float* __restrict__ p_arr,
    uint2* __restrict__ rec)
{
    __shared__ int curs[NBKT];
    for (int b = threadIdx.x; b < NBKT; b += 1024)
        curs[b] = offP[b * NBLK_P + blockIdx.x];
    __syncthreads();
    float dw = dotwe[0];
    int e0 = blockIdx.x * EPB, e1 = min(e0 + EPB, N_EDGES);
    for (int e = e0 + threadIdx.x; e < e1; e += 1024) {
        int d = dst[e], s = src[e];
        float lg = a_src[s] + a_dst[d] + dw * ew[e];
        lg = (lg >= 0.f) ? lg : NEG_SLOPE * lg;
        float p = __expf(lg);
        p_arr[e] = p;
        int pos = atomicAdd(&curs[d >> 7], 1);   // LDS atomic
        rec[pos] = make_uint2(((unsigned)(d & 127) << 17) | (unsigned)s,
                              __float_as_uint(p));
    }
}

// ---------------------------------------------------------------------------
// K_s2: one block per bucket. LDS counting-sort (local bases via LDS scan),
// per-node denom, alpha normalize, coalesced CSR writeout, xagg, off, denomG.
__global__ __launch_bounds__(256) void k_s2(
    const int* __restrict__ offP, const uint2* __restrict__ rec,
    const float* __restrict__ x, uint2* __restrict__ sa_srt,
    float* __restrict__ xagg8, float* __restrict__ denomG,
    int* __restrict__ off)
{
    __shared__ uint2 srt[S2_CAP];
    __shared__ int cntL[NB_BKT], fillL[NB_BKT], baseL[NB_BKT + 1];
    __shared__ int sc[NB_BKT];
    __shared__ float rden[NB_BKT];
    int b = blockIdx.x, tid = threadIdx.x;
    int g0 = offP[b * NBLK_P];
    int g1 = offP[(b + 1) * NBLK_P];     // b==NBKT-1 -> offP[NHIST] == N_EDGES
    int len = min(g1 - g0, S2_CAP);

    if (tid < NB_BKT) { cntL[tid] = 0; fillL[tid] = 0; }
    __syncthreads();

    // pass 1: count (records re-read from L2)
    for (int i = tid; i < len; i += 256)
        atomicAdd(&cntL[rec[g0 + i].x >> 17], 1);
    __syncthreads();

    // LDS scan over 128 counts -> baseL (exclusive)
    {
        int v = (tid < NB_BKT) ? cntL[tid] : 0;
        if (tid < NB_BKT) sc[tid] = v;
        __syncthreads();
        for (int o = 1; o < NB_BKT; o <<= 1) {
            int t = (tid >= o && tid < NB_BKT) ? sc[tid - o] : 0;
            __syncthreads();
            if (tid < NB_BKT) sc[tid] += t;
            __syncthreads();
        }
        if (tid < NB_BKT) baseL[tid + 1] = sc[tid];
        if (tid == 0) baseL[0] = 0;
    }
    __syncthreads();

    // pass 2: place into sorted LDS order
    for (int i = tid; i < len; i += 256) {
        uint2 r = rec[g0 + i];
        int dl = r.x >> 17;
        int p = baseL[dl] + atomicAdd(&fillL[dl], 1);
        if (p < S2_CAP) srt[p] = r;
    }
    __syncthreads();

    // per-node denom
    if (tid < NB_BKT) {
        int s0 = baseL[tid], s1 = baseL[tid + 1];
        float dsum = 0.f;
        for (int j = s0; j < s1; ++j) dsum += __uint_as_float(srt[j].y);
        int n = b * NB_BKT + tid;
        if (n < N_NODES) denomG[n] = dsum;
        rden[tid] = 1.0f / fmaxf(dsum, 1e-16f);
    }
    __syncthreads();

    // normalize alpha in LDS + coalesced CSR writeout {src, alpha}
    for (int i = tid; i < len; i += 256) {
        uint2 r = srt[i];
        int dl = r.x >> 17;
        float a = __uint_as_float(r.y) * rden[dl];
        srt[i].y = __float_as_uint(a);
        sa_srt[g0 + i] = make_uint2(r.x & 0x1FFFFu, __float_as_uint(a));
    }
    __syncthreads();

    // xagg (6-dim weighted x sum) + off
    if (tid < NB_BKT) {
        int n = b * NB_BKT + tid;
        if (n < N_NODES) {
            int s0 = baseL[tid], s1 = baseL[tid + 1];
            float ax0 = 0, ax1 = 0, ax2 = 0, ax3 = 0, ax4 = 0, ax5 = 0;
            for (int j = s0; j < s1; ++j) {
                uint2 r = srt[j];
                float a = __uint_as_float(r.y);
                const float2* xp = (const float2*)(x + (size_t)(r.x & 0x1FFFFu) * D_IN);
                float2 q0 = xp[0], q1 = xp[1], q2 = xp[2];
                ax0 += a * q0.x; ax1 += a * q0.y; ax2 += a * q1.x;
                ax3 += a * q1.y; ax4 += a * q2.x; ax5 += a * q2.y;
            }
            float dv = (s1 > s0) ? 1.0f : 0.0f;   // sum(alpha)=1 -> dinv=1
            float* xo = xagg8 + (size_t)n * 8;
            float4 lo = {dv, ax0, ax1, ax2};
            float4 hi = {ax3, ax4, ax5, 0.f};
            *(float4*)xo = lo;
            *(float4*)(xo + 4) = hi;
            off[n] = g0 + s0;
        }
    }
    if (b == NBKT - 1 && tid == 0) off[N_NODES] = g1;
}

// ---------------------------------------------------------------------------
// K_alpha: original-order alpha output (coalesced; denom gathered, L3-resident)
__global__ __launch_bounds__(256) void k_alpha(
    const float* __restrict__ p_arr, const int* __restrict__ dst,
    const float* __restrict__ denomG, float* __restrict__ alpha_out)
{
    int e = blockIdx.x * 256 + threadIdx.x;
    if (e >= N_EDGES) return;
    alpha_out[e] = p_arr[e] / fmaxf(denomG[dst[e]], 1e-16f);
}

// ---------------------------------------------------------------------------
// K_gcn_gather (2-phase): 4 nodes/block.
// P1: lane-per-edge parallel gather of {dinv_s*alpha, xagg[0..5]} -> LDS
//     (all 256 threads stage).
// P2: wave-per-node, 2 features/lane, broadcast ds_read_b128, per-feature acc.
#define GCAP 256
__global__ __launch_bounds__(256) void k_gcn_gather(
    const uint2* __restrict__ sa_srt, const int* __restrict__ off,
    const float* __restrict__ xagg8, const float* __restrict__ w_gat,
    const float* __restrict__ b_gat, float* __restrict__ agg)
{
    __shared__ float lds[GCAP * 12];
    int tid = threadIdx.x;
    int n0 = blockIdx.x * 4;
    int wid = tid >> 6, l = tid & 63;
    int n = n0 + wid;
    int beg0 = off[n0];
    int total = off[n0 + 4] - beg0;
    int nb = off[n] - beg0, ne = off[n + 1] - beg0;

    int kA = l, kB = l + 64;
    float wA0 = w_gat[0 * HID + kA], wA1 = w_gat[1 * HID + kA], wA2 = w_gat[2 * HID + kA];
    float wA3 = w_gat[3 * HID + kA], wA4 = w_gat[4 * HID + kA], wA5 = w_gat[5 * HID + kA];
    float wB0 = w_gat[0 * HID + kB], wB1 = w_gat[1 * HID + kB], wB2 = w_gat[2 * HID + kB];
    float wB3 = w_gat[3 * HID + kB], wB4 = w_gat[4 * HID + kB], wB5 = w_gat[5 * HID + kB];
    float bA = b_gat[kA], bB = b_gat[kB];
    float accA = 0.f, accB = 0.f;

    for (int base = 0; base < total; base += GCAP) {
        int cnt = min(GCAP, total - base);
        __syncthreads();
        if (tid < cnt) {
            int j = beg0 + base + tid;
            uint2 sa = sa_srt[j];                  // coalesced 8B
            float a = __uint_as_float(sa.y);
            const float4* xp = (const float4*)(xagg8 + (size_t)sa.x * 8);
            float4 lo = xp[0], hi = xp[1];         // {dinv_s,x0,x1,x2},{x3,x4,x5,-}
            float4 w0 = {lo.x * a, lo.y, lo.z, lo.w};
            float4 w1 = {hi.x, hi.y, hi.z, 0.f};
            *(float4*)(lds + tid * 12) = w0;
            *(float4*)(lds + tid * 12 + 4) = w1;
        }
        __syncthreads();
        int lo_t = nb - base; if (lo_t < 0) lo_t = 0;
        int hi_t = ne - base; if (hi_t > cnt) hi_t = cnt;
        for (int t = lo_t; t < hi_t; ++t) {
            float4 e0 = *(const float4*)(lds + t * 12);
            float4 e1 = *(const float4*)(lds + t * 12 + 4);
            float hA = bA, hB = bB;
            hA = fmaf(e0.y, wA0, hA); hB = fmaf(e0.y, wB0, hB);
            hA = fmaf(e0.z, wA1, hA); hB = fmaf(e0.z, wB1, hB);
            hA = fmaf(e0.w, wA2, hA); hB = fmaf(e0.w, wB2, hB);
            hA = fmaf(e1.x, wA3, hA); hB = fmaf(e1.x, wB3, hB);
            hA = fmaf(e1.y, wA4, hA); hB = fmaf(e1.y, wB4, hB);
            hA = fmaf(e1.z, wA5, hA); hB = fmaf(e1.z, wB5, hB);
            hA = fmaxf(hA, 0.f); hB = fmaxf(hB, 0.f);
            accA = fmaf(e0.x, hA, accA); accB = fmaf(e0.x, hB, accB);
        }
    }
    float dn = xagg8[(size_t)n * 8];
    agg[(size_t)n * HID + kA] = dn * accA;
    agg[(size_t)n * HID + kB] = dn * accB;
}

// ---------------------------------------------------------------------------
// K_dense2 (LDS-tiled GEMM): h2 = relu(agg @ w_gcn + b_gcn); out = h2 @ w_out
// + b_out. M=128 nodes x N=128 x K-chunks of 32, 256 threads, 8x8 register
// tile per thread; both operand streams from LDS. LDS 33 KB -> 4 blocks/CU.
#define DM 128
#define DK 32
__global__ __launch_bounds__(256, 4) void k_dense2(
    const float* __restrict__ agg, const float* __restrict__ w_gcn,
    const float* __restrict__ b_gcn, const float* __restrict__ w_out,
    const float* __restrict__ b_out, float* __restrict__ out)
{
    __shared__ float As[DK][DM + 4];   // [k][m]
    __shared__ float Bs[DK][HID];      // [k][n]
    int tid = threadIdx.x;
    int m0 = blockIdx.x * DM;
    int tx = tid & 15;            // col group: cols tx*8 .. tx*8+7
    int ty = tid >> 4;            // row group: rows ty*8 .. ty*8+7

    float acc[8][8];
#pragma unroll
    for (int r = 0; r < 8; ++r)
#pragma unroll
        for (int j = 0; j < 8; ++j) acc[r][j] = 0.f;

    for (int k0 = 0; k0 < HID; k0 += DK) {
        // stage A: agg[m0+m][k0+k] -> As[k][m]  (128m x 32k, coalesced f4)
#pragma unroll
        for (int q = 0; q < 4; ++q) {
            int idx4 = tid + q * 256;
            int m = idx4 >> 3;             // 8 float4 per row
            int k4 = (idx4 & 7) * 4;
            int gm = m0 + m;
            float4 v = (gm < N_NODES)
                ? *(const float4*)(agg + (size_t)gm * HID + k0 + k4)
                : make_float4(0.f, 0.f, 0.f, 0.f);
            As[k4 + 0][m] = v.x;
            As[k4 + 1][m] = v.y;
            As[k4 + 2][m] = v.z;
            As[k4 + 3][m] = v.w;
        }
        // stage B: w_gcn[k0+k][n] -> Bs[k][n]  (32k x 128n, coalesced f4)
#pragma unroll
        for (int q = 0; q < 4; ++q) {
            int idx4 = tid + q * 256;
            int k = idx4 >> 5;             // 32 float4 per row
            int n4 = (idx4 & 31) * 4;
            *(float4*)&Bs[k][n4] = *(const float4*)(w_gcn + (size_t)(k0 + k) * HID + n4);
        }
        __syncthreads();
#pragma unroll 4
        for (int k = 0; k < DK; ++k) {
            float4 w0 = *(const float4*)&Bs[k][tx * 8];
            float4 w1 = *(const float4*)&Bs[k][tx * 8 + 4];
            float4 h0 = *(const float4*)&As[k][ty * 8];
            float4 h1 = *(const float4*)&As[k][ty * 8 + 4];
            float hv[8] = {h0.x, h0.y, h0.z, h0.w, h1.x, h1.y, h1.z, h1.w};
            float wv[8] = {w0.x, w0.y, w0.z, w0.w, w1.x, w1.y, w1.z, w1.w};
#pragma unroll
            for (int r = 0; r < 8; ++r)
#pragma unroll
                for (int j = 0; j < 8; ++j)
                    acc[r][j] = fmaf(hv[r], wv[j], acc[r][j]);
        }
        __syncthreads();
    }

    // epilogue: bias + relu + 2-col head, reduce over the 16 col-groups
    float bb[8], wo0[8], wo1[8];
#pragma unroll
    for (int j = 0; j < 8; ++j) {
        int c = tx * 8 + j;
        bb[j] = b_gcn[c];
        wo0[j] = w_out[c * 2 + 0];
        wo1[j] = w_out[c * 2 + 1];
    }
#pragma unroll
    for (int r = 0; r < 8; ++r) {
        float p0 = 0.f, p1 = 0.f;
#pragma unroll
        for (int j = 0; j < 8; ++j) {
            float h2 = fmaxf(acc[r][j] + bb[j], 0.f);
            p0 = fmaf(h2, wo0[j], p0);
            p1 = fmaf(h2, wo1[j], p1);
        }
        // butterfly over tx (16 lanes within the wave's 64; masks stay <16)
        p0 += __shfl_xor(p0, 1);  p1 += __shfl_xor(p1, 1);
        p0 += __shfl_xor(p0, 2);  p1 += __shfl_xor(p1, 2);
        p0 += __shfl_xor(p0, 4);  p1 += __shfl_xor(p1, 4);
        p0 += __shfl_xor(p0, 8);  p1 += __shfl_xor(p1, 8);
        if (tx == 0) {
            int gm = m0 + ty * 8 + r;
            if (gm < N_NODES) {
                out[(size_t)gm * 2 + 0] = p0 + b_out[0];
                out[(size_t)gm * 2 + 1] = p1 + b_out[1];
            }
        }
    }
}

// ---------------------------------------------------------------------------
// K_copy_ei: edge_index (int) -> float output, vectorized int4 -> float4
__global__ __launch_bounds__(256) void k_copy_ei(
    const int* __restrict__ ei, float* __restrict__ out_ei)
{
    int i = blockIdx.x * 256 + threadIdx.x;   // quad index
    if (i < (2 * N_EDGES) / 4) {
        int4 v = ((const int4*)ei)[i];
        float4 f = {(float)v.x, (float)v.y, (float)v.z, (float)v.w};
        ((float4*)out_ei)[i] = f;
    }
}

// ---------------------------------------------------------------------------
extern "C" void kernel_launch(void* const* d_in, const int* in_sizes, int n_in,
                              void* d_out, int out_size, void* d_ws, size_t ws_size,
                              hipStream_t stream)
{
    const float* x        = (const float*)d_in[0];
    const int*   ei       = (const int*)d_in[1];
    const float* ew       = (const float*)d_in[2];
    const float* w_gat    = (const float*)d_in[3];
    const float* att_src  = (const float*)d_in[4];
    const float* att_dst  = (const float*)d_in[5];
    const float* w_edge   = (const float*)d_in[6];
    const float* att_edge = (const float*)d_in[7];
    const float* b_gat    = (const float*)d_in[8];
    const float* w_gcn    = (const float*)d_in[9];
    const float* b_gcn    = (const float*)d_in[10];
    const float* w_out    = (const float*)d_in[11];
    const float* b_out    = (const float*)d_in[12];

    const int* src = ei;
    const int* dst = ei + N_EDGES;

    float* out_head  = (float*)d_out;
    float* out_ei    = out_head + 2 * N_NODES;
    float* out_alpha = out_ei + 2 * N_EDGES;

    char* ws = (char*)d_ws;
    size_t o = 0;
    auto alloc = [&](size_t bytes) -> char* {
        char* p = ws + o;
        o = (o + bytes + 255) & ~(size_t)255;
        return p;
    };
    float* agg    = (float*)alloc((size_t)N_NODES * HID * 4);   // 51.2 MB
    uint2* rec    = (uint2*)alloc((size_t)N_EDGES * 8);         // 12.8 MB
    uint2* sa_srt = (uint2*)alloc((size_t)N_EDGES * 8);         // 12.8 MB
    float* p_arr  = (float*)alloc((size_t)N_EDGES * 4);         // 6.4 MB
    float* xagg8  = (float*)alloc((size_t)N_NODES * 8 * 4);     // 3.2 MB
    int*   histG  = (int*)alloc((size_t)NHIST * 4);             // 0.8 MB
    int*   incl   = (int*)alloc((size_t)NHIST * 4);
    int*   offP   = (int*)alloc((size_t)(NHIST + 1) * 4);
    float* a_src  = (float*)alloc(N_NODES * 4);
    float* a_dst  = (float*)alloc(N_NODES * 4);
    float* denomG = (float*)alloc(N_NODES * 4);
    int*   off    = (int*)alloc((N_NODES + 1) * 4);
    int*   bsums  = (int*)alloc(512 * 4);
    int*   boffs  = (int*)alloc(512 * 4);
    float* w_as   = (float*)alloc(D_IN * 4);
    float* w_ad   = (float*)alloc(D_IN * 4);
    float* dotwe  = (float*)alloc(4);
    (void)ws_size; (void)out_size; (void)n_in; (void)in_sizes;

    const int NB_NODE = (N_NODES + 255) / 256;          // 391
    const int NB_EDGE = (N_EDGES + 255) / 256;          // 6250
    const int NB_SCANP = (NHIST + 511) / 512;           // 391

    k_prep<<<1, 128, 0, stream>>>(w_gat, att_src, att_dst, w_edge, att_edge,
                                  w_as, w_ad, dotwe);
    k_asrc<<<NB_NODE, 256, 0, stream>>>(x, w_as, w_ad, a_src, a_dst);
    k_hist<<<NBLK_P, 1024, 0, stream>>>(dst, histG);
    k_scan1<<<NB_SCANP, 512, 0, stream>>>(histG, incl, bsums, NHIST);
    k_scan2<<<1, 512, 0, stream>>>(bsums, boffs, NB_SCANP);
    k_scan3<<<NB_SCANP, 512, 0, stream>>>(histG, incl, boffs, offP, NHIST);
    k_part<<<NBLK_P, 1024, 0, stream>>>(src, dst, ew, a_src, a_dst, dotwe,
                                        offP, p_arr, rec);
    k_s2<<<NBKT, 256, 0, stream>>>(offP, rec, x, sa_srt, xagg8, denomG, off);
    k_alpha<<<NB_EDGE, 256, 0, stream>>>(p_arr, dst, denomG, out_alpha);
    k_gcn_gather<<<N_NODES / 4, 256, 0, stream>>>(
        sa_srt, off, xagg8, w_gat, b_gat, agg);
    k_dense2<<<(N_NODES + DM - 1) / DM, 256, 0, stream>>>(
        agg, w_gcn, b_gcn, w_out, b_out, out_head);
    k_copy_ei<<<(2 * N_EDGES) / 4 / 256 + 1, 256, 0, stream>>>(ei, out_ei);
}

// Round 10
// 295.053 us; speedup vs baseline: 1.0294x; 1.0083x over previous
//
#include <hip/hip_runtime.h>
#include <hip/hip_bf16.h>
#include <math.h>

#define N_NODES 100000
#define N_EDGES 1600000
#define HID 128
#define D_IN 6
#define NEG_SLOPE 0.2f

#define NB_BKT 128                       // nodes per bucket
#define NBKT 782                         // ceil(N_NODES / NB_BKT)
#define NBLK_P 256                       // partition blocks (1024 thr each)
#define EPB ((N_EDGES + NBLK_P - 1) / NBLK_P)   // 6250 edges per partition block
#define NHIST (NBKT * NBLK_P)            // 200192
#define S2_CAP 3072                      // max edges per bucket (mean 2048, +22 sigma)

__device__ inline float2 fma2(float s, float2 w, float2 c) {
    return make_float2(fmaf(s, w.x, c.x), fmaf(s, w.y, c.y));
}

// ---------------------------------------------------------------------------
// K_prep (1 block): w_as = w_gat@att_src (6), w_ad = w_gat@att_dst (6),
// dotwe = w_edge . att_edge
__global__ __launch_bounds__(128) void k_prep(
    const float* __restrict__ w_gat, const float* __restrict__ att_src,
    const float* __restrict__ att_dst, const float* __restrict__ w_edge,
    const float* __restrict__ att_edge, float* __restrict__ w_as,
    float* __restrict__ w_ad, float* __restrict__ dotwe)
{
    int tid = threadIdx.x;
    __shared__ float red[4];
    float as = att_src[tid], ad = att_dst[tid];

    float v = w_edge[tid] * att_edge[tid];
    for (int o = 32; o; o >>= 1) v += __shfl_down(v, o);
    if ((tid & 63) == 0) red[tid >> 6] = v;
    __syncthreads();
    if (tid == 0) dotwe[0] = red[0] + red[1];

#pragma unroll
    for (int i = 0; i < D_IN; ++i) {
        float wv = w_gat[i * HID + tid];
        float v1 = wv * as, v2 = wv * ad;
        for (int o = 32; o; o >>= 1) {
            v1 += __shfl_down(v1, o);
            v2 += __shfl_down(v2, o);
        }
        __syncthreads();
        if ((tid & 63) == 0) { red[(tid >> 6) * 2] = v1; red[(tid >> 6) * 2 + 1] = v2; }
        __syncthreads();
        if (tid == 0) { w_as[i] = red[0] + red[2]; w_ad[i] = red[1] + red[3]; }
    }
}

// ---------------------------------------------------------------------------
__global__ __launch_bounds__(256) void k_asrc(
    const float* __restrict__ x, const float* __restrict__ w_as,
    const float* __restrict__ w_ad, float* __restrict__ a_src,
    float* __restrict__ a_dst)
{
    int n = blockIdx.x * 256 + threadIdx.x;
    if (n >= N_NODES) return;
    float s0 = 0.f, s1 = 0.f;
#pragma unroll
    for (int i = 0; i < D_IN; ++i) {
        float xv = x[n * D_IN + i];
        s0 += xv * w_as[i];
        s1 += xv * w_ad[i];
    }
    a_src[n] = s0;
    a_dst[n] = s1;
}

// ---------------------------------------------------------------------------
// K_hist: per-block LDS histogram over dst-buckets (no device atomics)
__global__ __launch_bounds__(1024) void k_hist(
    const int* __restrict__ dst, int* __restrict__ histG)
{
    __shared__ int h[NBKT];
    for (int b = threadIdx.x; b < NBKT; b += 1024) h[b] = 0;
    __syncthreads();
    int e0 = blockIdx.x * EPB, e1 = min(e0 + EPB, N_EDGES);
    for (int e = e0 + threadIdx.x; e < e1; e += 1024)
        atomicAdd(&h[dst[e] >> 7], 1);           // LDS atomic (CU-local)
    __syncthreads();
    for (int b = threadIdx.x; b < NBKT; b += 1024)
        histG[b * NBLK_P + blockIdx.x] = h[b];   // bucket-major layout
}

// ---------------------------------------------------------------------------
// generic exclusive scan (3 kernels, 512-thread blocks), n arbitrary
__global__ __launch_bounds__(512) void k_scan1(
    const int* __restrict__ in, int* __restrict__ incl, int* __restrict__ bsums,
    int n)
{
    __shared__ int s[512];
    int tid = threadIdx.x;
    int i = blockIdx.x * 512 + tid;
    int v = (i < n) ? in[i] : 0;
    s[tid] = v;
    __syncthreads();
    for (int o = 1; o < 512; o <<= 1) {
        int t = (tid >= o) ? s[tid - o] : 0;
        __syncthreads();
        s[tid] += t;
        __syncthreads();
    }
    if (i < n) incl[i] = s[tid];
    if (tid == 511) bsums[blockIdx.x] = s[511];
}

__global__ __launch_bounds__(512) void k_scan2(
    const int* __restrict__ bsums, int* __restrict__ boffs, int nb)
{
    __shared__ int s[512];
    int tid = threadIdx.x;
    int v = (tid < nb) ? bsums[tid] : 0;
    s[tid] = v;
    __syncthreads();
    for (int o = 1; o < 512; o <<= 1) {
        int t = (tid >= o) ? s[tid - o] : 0;
        __syncthreads();
        s[tid] += t;
        __syncthreads();
    }
    if (tid < nb) boffs[tid] = s[tid] - v;  // exclusive
}

__global__ __launch_bounds__(512) void k_scan3(
    const int* __restrict__ in, const int* __restrict__ incl,
    const int* __restrict__ boffs, int* __restrict__ off, int n)
{
    int i = blockIdx.x * 512 + threadIdx.x;
    if (i < n) {
        int b = boffs[blockIdx.x];
        off[i] = b + incl[i] - in[i];
        if (i == n - 1) off[n] = b + incl[i];
    }
}

// ---------------------------------------------------------------------------
// K_part: stable partition into dst-buckets. Each (block,bucket) writes into
// its exclusive range (~8 records = 1 cache line) via an LDS cursor -> no
// device atomics, line-local writes. 1024 thr/block x 256 blocks for latency
// hiding of the random a_src/a_dst gathers.
__global__ __launch_bounds__(1024) void k_part(
    const int* __restrict__ src, const int* __restrict__ dst,
    const float* __restrict__ ew, const float* __restrict__ a_src,
    const float* __restrict__ a_dst, const float* __restrict__ dotwe,
    const int* __restrict__ offP, float* __restrict__ p_arr,
    uint2* __restrict__ rec)
{
    __shared__ int curs[NBKT];
    for (int b = threadIdx.x; b < NBKT; b += 1024)
        curs[b] = offP[b * NBLK_P + blockIdx.x];
    __syncthreads();
    float dw = dotwe[0];
    int e0 = blockIdx.x * EPB, e1 = min(e0 + EPB, N_EDGES);
    for (int e = e0 + threadIdx.x; e < e1; e += 1024) {
        int d = dst[e], s = src[e];
        float lg = a_src[s] + a_dst[d] + dw * ew[e];
        lg = (lg >= 0.f) ? lg : NEG_SLOPE * lg;
        float p = __expf(lg);
        p_arr[e] = p;
        int pos = atomicAdd(&curs[d >> 7], 1);   // LDS atomic
        rec[pos] = make_uint2(((unsigned)(d & 127) << 17) | (unsigned)s,
                              __float_as_uint(p));
    }
}

// ---------------------------------------------------------------------------
// K_s2: one block per bucket. LDS counting-sort (local bases via LDS scan),
// per-node denom, alpha normalize, coalesced CSR writeout, xagg, off, denomG.
__global__ __launch_bounds__(256) void k_s2(
    const int* __restrict__ offP, const uint2* __restrict__ rec,
    const float* __restrict__ x, uint2* __restrict__ sa_srt,
    float* __restrict__ xagg8, float* __restrict__ denomG,
    int* __restrict__ off)
{
    __shared__ uint2 srt[S2_CAP];
    __shared__ int cntL[NB_BKT], fillL[NB_BKT], baseL[NB_BKT + 1];
    __shared__ int sc[NB_BKT];
    __shared__ float rden[NB_BKT];
    int b = blockIdx.x, tid = threadIdx.x;
    int g0 = offP[b * NBLK_P];
    int g1 = offP[(b + 1) * NBLK_P];     // b==NBKT-1 -> offP[NHIST] == N_EDGES
    int len = min(g1 - g0, S2_CAP);

    if (tid < NB_BKT) { cntL[tid] = 0; fillL[tid] = 0; }
    __syncthreads();

    // pass 1: count (records re-read from L2)
    for (int i = tid; i < len; i += 256)
        atomicAdd(&cntL[rec[g0 + i].x >> 17], 1);
    __syncthreads();

    // LDS scan over 128 counts -> baseL (exclusive)
    {
        int v = (tid < NB_BKT) ? cntL[tid] : 0;
        if (tid < NB_BKT) sc[tid] = v;
        __syncthreads();
        for (int o = 1; o < NB_BKT; o <<= 1) {
            int t = (tid >= o && tid < NB_BKT) ? sc[tid - o] : 0;
            __syncthreads();
            if (tid < NB_BKT) sc[tid] += t;
            __syncthreads();
        }
        if (tid < NB_BKT) baseL[tid + 1] = sc[tid];
        if (tid == 0) baseL[0] = 0;
    }
    __syncthreads();

    // pass 2: place into sorted LDS order
    for (int i = tid; i < len; i += 256) {
        uint2 r = rec[g0 + i];
        int dl = r.x >> 17;
        int p = baseL[dl] + atomicAdd(&fillL[dl], 1);
        if (p < S2_CAP) srt[p] = r;
    }
    __syncthreads();

    // per-node denom
    if (tid < NB_BKT) {
        int s0 = baseL[tid], s1 = baseL[tid + 1];
        float dsum = 0.f;
        for (int j = s0; j < s1; ++j) dsum += __uint_as_float(srt[j].y);
        int n = b * NB_BKT + tid;
        if (n < N_NODES) denomG[n] = dsum;
        rden[tid] = 1.0f / fmaxf(dsum, 1e-16f);
    }
    __syncthreads();

    // normalize alpha in LDS + coalesced CSR writeout {src, alpha}
    for (int i = tid; i < len; i += 256) {
        uint2 r = srt[i];
        int dl = r.x >> 17;
        float a = __uint_as_float(r.y) * rden[dl];
        srt[i].y = __float_as_uint(a);
        sa_srt[g0 + i] = make_uint2(r.x & 0x1FFFFu, __float_as_uint(a));
    }
    __syncthreads();

    // xagg (6-dim weighted x sum) + off
    if (tid < NB_BKT) {
        int n = b * NB_BKT + tid;
        if (n < N_NODES) {
            int s0 = baseL[tid], s1 = baseL[tid + 1];
            float ax0 = 0, ax1 = 0, ax2 = 0, ax3 = 0, ax4 = 0, ax5 = 0;
            for (int j = s0; j < s1; ++j) {
                uint2 r = srt[j];
                float a = __uint_as_float(r.y);
                const float2* xp = (const float2*)(x + (size_t)(r.x & 0x1FFFFu) * D_IN);
                float2 q0 = xp[0], q1 = xp[1], q2 = xp[2];
                ax0 += a * q0.x; ax1 += a * q0.y; ax2 += a * q1.x;
                ax3 += a * q1.y; ax4 += a * q2.x; ax5 += a * q2.y;
            }
            float dv = (s1 > s0) ? 1.0f : 0.0f;   // sum(alpha)=1 -> dinv=1
            float* xo = xagg8 + (size_t)n * 8;
            float4 lo = {dv, ax0, ax1, ax2};
            float4 hi = {ax3, ax4, ax5, 0.f};
            *(float4*)xo = lo;
            *(float4*)(xo + 4) = hi;
            off[n] = g0 + s0;
        }
    }
    if (b == NBKT - 1 && tid == 0) off[N_NODES] = g1;
}

// ---------------------------------------------------------------------------
// K_alpha: original-order alpha output (coalesced; denom gathered, L3-resident)
__global__ __launch_bounds__(256) void k_alpha(
    const float* __restrict__ p_arr, const int* __restrict__ dst,
    const float* __restrict__ denomG, float* __restrict__ alpha_out)
{
    int e = blockIdx.x * 256 + threadIdx.x;
    if (e >= N_EDGES) return;
    alpha_out[e] = p_arr[e] / fmaxf(denomG[dst[e]], 1e-16f);
}

// ---------------------------------------------------------------------------
// K_gcn_gather v3: 8 waves/block, one node per wave, NO __syncthreads.
// Each wave stages its node's edges into a private LDS region (same-wave
// write->read, compiler-inserted lgkmcnt only), then consumes with a 2-edge
// unrolled broadcast-read loop. float2 math to encourage v_pk_fma_f32.
#define WCAP 64
__global__ __launch_bounds__(512) void k_gcn_gather(
    const uint2* __restrict__ sa_srt, const int* __restrict__ off,
    const float* __restrict__ xagg8, const float* __restrict__ w_gat,
    const float* __restrict__ b_gat, float* __restrict__ agg)
{
    __shared__ float lds[8][WCAP * 12];   // 24 KB; stride 12 floats (16B-aligned)
    int tid = threadIdx.x;
    int w = tid >> 6, l = tid & 63;
    int n = blockIdx.x * 8 + w;
    int beg = off[n], end = off[n + 1];
    float* reg = lds[w];

    // per-lane weight pairs: features (l, l+64)
    float2 wp[D_IN], bp;
#pragma unroll
    for (int i = 0; i < D_IN; ++i)
        wp[i] = make_float2(w_gat[i * HID + l], w_gat[i * HID + l + 64]);
    bp = make_float2(b_gat[l], b_gat[l + 64]);
    float2 acc = make_float2(0.f, 0.f);

    for (int base = beg; base < end; base += WCAP) {
        int cnt = min(WCAP, end - base);
        if (l < cnt) {
            uint2 sa = sa_srt[base + l];           // coalesced 8B
            float a = __uint_as_float(sa.y);
            const float4* xp = (const float4*)(xagg8 + (size_t)sa.x * 8);
            float4 lo = xp[0], hi = xp[1];         // {dinv_s,x0,x1,x2},{x3,x4,x5,-}
            float4 w0 = {lo.x * a, lo.y, lo.z, lo.w};
            float4 w1 = {hi.x, hi.y, hi.z, 0.f};
            *(float4*)(reg + l * 12) = w0;
            *(float4*)(reg + l * 12 + 4) = w1;
        }
        // same-wave LDS dependency: no barrier needed
        int t = 0;
        for (; t + 2 <= cnt; t += 2) {
            float4 a0 = *(const float4*)(reg + t * 12);
            float4 a1 = *(const float4*)(reg + t * 12 + 4);
            float4 b0 = *(const float4*)(reg + (t + 1) * 12);
            float4 b1 = *(const float4*)(reg + (t + 1) * 12 + 4);
            float2 hA = bp, hB = bp;
            hA = fma2(a0.y, wp[0], hA);  hB = fma2(b0.y, wp[0], hB);
            hA = fma2(a0.z, wp[1], hA);  hB = fma2(b0.z, wp[1], hB);
            hA = fma2(a0.w, wp[2], hA);  hB = fma2(b0.w, wp[2], hB);
            hA = fma2(a1.x, wp[3], hA);  hB = fma2(b1.x, wp[3], hB);
            hA = fma2(a1.y, wp[4], hA);  hB = fma2(b1.y, wp[4], hB);
            hA = fma2(a1.z, wp[5], hA);  hB = fma2(b1.z, wp[5], hB);
            hA.x = fmaxf(hA.x, 0.f); hA.y = fmaxf(hA.y, 0.f);
            hB.x = fmaxf(hB.x, 0.f); hB.y = fmaxf(hB.y, 0.f);
            acc = fma2(a0.x, hA, acc);
            acc = fma2(b0.x, hB, acc);
        }
        if (t < cnt) {
            float4 a0 = *(const float4*)(reg + t * 12);
            float4 a1 = *(const float4*)(reg + t * 12 + 4);
            float2 hA = bp;
            hA = fma2(a0.y, wp[0], hA);
            hA = fma2(a0.z, wp[1], hA);
            hA = fma2(a0.w, wp[2], hA);
            hA = fma2(a1.x, wp[3], hA);
            hA = fma2(a1.y, wp[4], hA);
            hA = fma2(a1.z, wp[5], hA);
            hA.x = fmaxf(hA.x, 0.f); hA.y = fmaxf(hA.y, 0.f);
            acc = fma2(a0.x, hA, acc);
        }
    }
    float dn = xagg8[(size_t)n * 8];
    agg[(size_t)n * HID + l] = dn * acc.x;
    agg[(size_t)n * HID + l + 64] = dn * acc.y;
}

// ---------------------------------------------------------------------------
// K_dense2 (LDS-tiled GEMM): h2 = relu(agg @ w_gcn + b_gcn); out = h2 @ w_out
// + b_out. M=128 nodes x N=128 x K-chunks of 32, 256 threads, 8x8 register
// tile per thread; both operand streams from LDS. LDS 33 KB -> 4 blocks/CU.
#define DM 128
#define DK 32
__global__ __launch_bounds__(256, 4) void k_dense2(
    const float* __restrict__ agg, const float* __restrict__ w_gcn,
    const float* __restrict__ b_gcn, const float* __restrict__ w_out,
    const float* __restrict__ b_out, float* __restrict__ out)
{
    __shared__ float As[DK][DM + 4];   // [k][m]
    __shared__ float Bs[DK][HID];      // [k][n]
    int tid = threadIdx.x;
    int m0 = blockIdx.x * DM;
    int tx = tid & 15;            // col group: cols tx*8 .. tx*8+7
    int ty = tid >> 4;            // row group: rows ty*8 .. ty*8+7

    float acc[8][8];
#pragma unroll
    for (int r = 0; r < 8; ++r)
#pragma unroll
        for (int j = 0; j < 8; ++j) acc[r][j] = 0.f;

    for (int k0 = 0; k0 < HID; k0 += DK) {
        // stage A: agg[m0+m][k0+k] -> As[k][m]  (128m x 32k, coalesced f4)
#pragma unroll
        for (int q = 0; q < 4; ++q) {
            int idx4 = tid + q * 256;
            int m = idx4 >> 3;             // 8 float4 per row
            int k4 = (idx4 & 7) * 4;
            int gm = m0 + m;
            float4 v = (gm < N_NODES)
                ? *(const float4*)(agg + (size_t)gm * HID + k0 + k4)
                : make_float4(0.f, 0.f, 0.f, 0.f);
            As[k4 + 0][m] = v.x;
            As[k4 + 1][m] = v.y;
            As[k4 + 2][m] = v.z;
            As[k4 + 3][m] = v.w;
        }
        // stage B: w_gcn[k0+k][n] -> Bs[k][n]  (32k x 128n, coalesced f4)
#pragma unroll
        for (int q = 0; q < 4; ++q) {
            int idx4 = tid + q * 256;
            int k = idx4 >> 5;             // 32 float4 per row
            int n4 = (idx4 & 31) * 4;
            *(float4*)&Bs[k][n4] = *(const float4*)(w_gcn + (size_t)(k0 + k) * HID + n4);
        }
        __syncthreads();
#pragma unroll 4
        for (int k = 0; k < DK; ++k) {
            float4 w0 = *(const float4*)&Bs[k][tx * 8];
            float4 w1 = *(const float4*)&Bs[k][tx * 8 + 4];
            float4 h0 = *(const float4*)&As[k][ty * 8];
            float4 h1 = *(const float4*)&As[k][ty * 8 + 4];
            float hv[8] = {h0.x, h0.y, h0.z, h0.w, h1.x, h1.y, h1.z, h1.w};
            float wv[8] = {w0.x, w0.y, w0.z, w0.w, w1.x, w1.y, w1.z, w1.w};
#pragma unroll
            for (int r = 0; r < 8; ++r)
#pragma unroll
                for (int j = 0; j < 8; ++j)
                    acc[r][j] = fmaf(hv[r], wv[j], acc[r][j]);
        }
        __syncthreads();
    }

    // epilogue: bias + relu + 2-col head, reduce over the 16 col-groups
    float bb[8], wo0[8], wo1[8];
#pragma unroll
    for (int j = 0; j < 8; ++j) {
        int c = tx * 8 + j;
        bb[j] = b_gcn[c];
        wo0[j] = w_out[c * 2 + 0];
        wo1[j] = w_out[c * 2 + 1];
    }
#pragma unroll
    for (int r = 0; r < 8; ++r) {
        float p0 = 0.f, p1 = 0.f;
#pragma unroll
        for (int j = 0; j < 8; ++j) {
            float h2 = fmaxf(acc[r][j] + bb[j], 0.f);
            p0 = fmaf(h2, wo0[j], p0);
            p1 = fmaf(h2, wo1[j], p1);
        }
        // butterfly over tx (16 lanes within the wave's 64; masks stay <16)
        p0 += __shfl_xor(p0, 1);  p1 += __shfl_xor(p1, 1);
        p0 += __shfl_xor(p0, 2);  p1 += __shfl_xor(p1, 2);
        p0 += __shfl_xor(p0, 4);  p1 += __shfl_xor(p1, 4);
        p0 += __shfl_xor(p0, 8);  p1 += __shfl_xor(p1, 8);
        if (tx == 0) {
            int gm = m0 + ty * 8 + r;
            if (gm < N_NODES) {
                out[(size_t)gm * 2 + 0] = p0 + b_out[0];
                out[(size_t)gm * 2 + 1] = p1 + b_out[1];
            }
        }
    }
}

// ---------------------------------------------------------------------------
// K_copy_ei: edge_index (int) -> float output, vectorized int4 -> float4
__global__ __launch_bounds__(256) void k_copy_ei(
    const int* __restrict__ ei, float* __restrict__ out_ei)
{
    int i = blockIdx.x * 256 + threadIdx.x;   // quad index
    if (i < (2 * N_EDGES) / 4) {
        int4 v = ((const int4*)ei)[i];
        float4 f = {(float)v.x, (float)v.y, (float)v.z, (float)v.w};
        ((float4*)out_ei)[i] = f;
    }
}

// ---------------------------------------------------------------------------
extern "C" void kernel_launch(void* const* d_in, const int* in_sizes, int n_in,
                              void* d_out, int out_size, void* d_ws, size_t ws_size,
                              hipStream_t stream)
{
    const float* x        = (const float*)d_in[0];
    const int*   ei       = (const int*)d_in[1];
    const float* ew       = (const float*)d_in[2];
    const float* w_gat    = (const float*)d_in[3];
    const float* att_src  = (const float*)d_in[4];
    const float* att_dst  = (const float*)d_in[5];
    const float* w_edge   = (const float*)d_in[6];
    const float* att_edge = (const float*)d_in[7];
    const float* b_gat    = (const float*)d_in[8];
    const float* w_gcn    = (const float*)d_in[9];
    const float* b_gcn    = (const float*)d_in[10];
    const float* w_out    = (const float*)d_in[11];
    const float* b_out    = (const float*)d_in[12];

    const int* src = ei;
    const int* dst = ei + N_EDGES;

    float* out_head  = (float*)d_out;
    float* out_ei    = out_head + 2 * N_NODES;
    float* out_alpha = out_ei + 2 * N_EDGES;

    char* ws = (char*)d_ws;
    size_t o = 0;
    auto alloc = [&](size_t bytes) -> char* {
        char* p = ws + o;
        o = (o + bytes + 255) & ~(size_t)255;
        return p;
    };
    float* agg    = (float*)alloc((size_t)N_NODES * HID * 4);   // 51.2 MB
    uint2* rec    = (uint2*)alloc((size_t)N_EDGES * 8);         // 12.8 MB
    uint2* sa_srt = (uint2*)alloc((size_t)N_EDGES * 8);         // 12.8 MB
    float* p_arr  = (float*)alloc((size_t)N_EDGES * 4);         // 6.4 MB
    float* xagg8  = (float*)alloc((size_t)N_NODES * 8 * 4);     // 3.2 MB
    int*   histG  = (int*)alloc((size_t)NHIST * 4);             // 0.8 MB
    int*   incl   = (int*)alloc((size_t)NHIST * 4);
    int*   offP   = (int*)alloc((size_t)(NHIST + 1) * 4);
    float* a_src  = (float*)alloc(N_NODES * 4);
    float* a_dst  = (float*)alloc(N_NODES * 4);
    float* denomG = (float*)alloc(N_NODES * 4);
    int*   off    = (int*)alloc((N_NODES + 1) * 4);
    int*   bsums  = (int*)alloc(512 * 4);
    int*   boffs  = (int*)alloc(512 * 4);
    float* w_as   = (float*)alloc(D_IN * 4);
    float* w_ad   = (float*)alloc(D_IN * 4);
    float* dotwe  = (float*)alloc(4);
    (void)ws_size; (void)out_size; (void)n_in; (void)in_sizes;

    const int NB_NODE = (N_NODES + 255) / 256;          // 391
    const int NB_EDGE = (N_EDGES + 255) / 256;          // 6250
    const int NB_SCANP = (NHIST + 511) / 512;           // 391

    k_prep<<<1, 128, 0, stream>>>(w_gat, att_src, att_dst, w_edge, att_edge,
                                  w_as, w_ad, dotwe);
    k_asrc<<<NB_NODE, 256, 0, stream>>>(x, w_as, w_ad, a_src, a_dst);
    k_hist<<<NBLK_P, 1024, 0, stream>>>(dst, histG);
    k_scan1<<<NB_SCANP, 512, 0, stream>>>(histG, incl, bsums, NHIST);
    k_scan2<<<1, 512, 0, stream>>>(bsums, boffs, NB_SCANP);
    k_scan3<<<NB_SCANP, 512, 0, stream>>>(histG, incl, boffs, offP, NHIST);
    k_part<<<NBLK_P, 1024, 0, stream>>>(src, dst, ew, a_src, a_dst, dotwe,
                                        offP, p_arr, rec);
    k_s2<<<NBKT, 256, 0, stream>>>(offP, rec, x, sa_srt, xagg8, denomG, off);
    k_alpha<<<NB_EDGE, 256, 0, stream>>>(p_arr, dst, denomG, out_alpha);
    k_gcn_gather<<<N_NODES / 8, 512, 0, stream>>>(
        sa_srt, off, xagg8, w_gat, b_gat, agg);
    k_dense2<<<(N_NODES + DM - 1) / DM, 256, 0, stream>>>(
        agg, w_gcn, b_gcn, w_out, b_out, out_head);
    k_copy_ei<<<(2 * N_EDGES) / 4 / 256 + 1, 256, 0, stream>>>(ei, out_ei);
}